// Round 7
// baseline (1928.606 us; speedup 1.0000x reference)
//
#include <hip/hip_runtime.h>

#define D 64
#define CAP 64   // adjacency bucket capacity; Poisson(20) => P(deg>64) ~ 1e-17

// ---------------------------------------------------------------------------
// Kernel 0: zero the cursor array (kernel, not hipMemsetAsync: stay
// unquestionably graph-capture-safe).
// ---------------------------------------------------------------------------
__global__ __launch_bounds__(256) void zero_cursor_kernel(int* __restrict__ cursor,
                                                          int n)
{
    const int i = blockIdx.x * blockDim.x + threadIdx.x;
    if (i < n) cursor[i] = 0;
}

// ---------------------------------------------------------------------------
// Kernel 1: fused dual GEMM, LDS-staged, MATRIX-SPLIT ACROSS WAVES.
//   out  = verts @ w0 + b0      (waves 0,1)
//   vw1  = verts @ w1 + b1      (waves 2,3)
// Round-5 post-mortem: the both-matrices-per-wave version needed ~176 VGPRs,
// the allocator capped at 128 and spilled the weight arrays -> 2.2 GB scratch
// traffic, VALUBusy 2.9%, 831 us. This version gives each wave ONE weight
// array (wc[64]) + acc[32] ~= 115 VGPRs -> no spill.
// Block = 256 threads, 64 rows staged in LDS with coalesced float4 loads;
// wave (mat, rhalf) computes rows rhalf*32..+31 of product `mat`; lane l owns
// output column l; row fragments are wave-uniform ds_read_b128 broadcasts.
// ---------------------------------------------------------------------------
__global__ __launch_bounds__(256, 2) void gemm2_kernel(
    const float* __restrict__ verts,
    const float* __restrict__ w0, const float* __restrict__ b0,
    const float* __restrict__ w1, const float* __restrict__ b1,
    float* __restrict__ out, float* __restrict__ vw1, int nrows)
{
    __shared__ float tile[64][D];        // 16 KiB
    const int tid   = threadIdx.x;
    const int lane  = tid & 63;
    const int wid   = tid >> 6;          // 0..3
    const int mat   = wid >> 1;          // 0 -> w0/out, 1 -> w1/vw1
    const int rhalf = wid & 1;           // rows 0-31 or 32-63 of the tile
    const int base  = blockIdx.x * 64;
    if (base >= nrows) return;

    const float* w = mat ? w1 : w0;
    const float* b = mat ? b1 : b0;
    float*       o = mat ? vw1 : out;

    // This wave's weight columns: wc[k] = w[k][lane]. Coalesced, L2-hot.
    float wc[D];
#pragma unroll
    for (int k = 0; k < D; ++k) wc[k] = w[k * D + lane];
    const float bias = b[lane];

    // Stage up to 64 rows, coalesced float4, all 256 threads.
    int rows = nrows - base; if (rows > 64) rows = 64;
    {
        const float4* src = (const float4*)(verts + (size_t)base * D);
        float4* dst = (float4*)(&tile[0][0]);
        for (int j = tid; j < rows * (D / 4); j += 256) dst[j] = src[j];
    }
    __syncthreads();

    const int r0 = rhalf * 32;
    float acc[32];
#pragma unroll
    for (int r = 0; r < 32; ++r) acc[r] = bias;

#pragma unroll
    for (int r = 0; r < 32; ++r) {
#pragma unroll
        for (int k4 = 0; k4 < D / 4; ++k4) {
            // wave-uniform address -> single broadcast ds_read_b128
            const float4 f = *(const float4*)(&tile[r0 + r][k4 * 4]);
            acc[r] = fmaf(f.x, wc[k4 * 4 + 0], acc[r]);
            acc[r] = fmaf(f.y, wc[k4 * 4 + 1], acc[r]);
            acc[r] = fmaf(f.z, wc[k4 * 4 + 2], acc[r]);
            acc[r] = fmaf(f.w, wc[k4 * 4 + 3], acc[r]);
        }
    }

    float* po = o + (size_t)(base + r0) * D + lane;   // coalesced stores
#pragma unroll
    for (int r = 0; r < 32; ++r) {
        if (base + r0 + r < nrows) po[(size_t)r * D] = acc[r];
    }
}

// ---------------------------------------------------------------------------
// Kernel 2: bucket neighbor IDs into fixed-capacity per-vertex lists.
// 2M int atomics on a 400 KB cursor array (vs 128M fp32 atomics in round 2).
// Overflow (statistically impossible here, but correct for any input) falls
// back to direct fp32 atomics into out.
// ---------------------------------------------------------------------------
__global__ __launch_bounds__(256) void build_adj_kernel(
    const int* __restrict__ edges, int* __restrict__ cursor,
    int* __restrict__ adj, const float* __restrict__ vw1,
    float* __restrict__ out, int nedges)
{
    const int e = blockIdx.x * blockDim.x + threadIdx.x;
    if (e >= nedges) return;
    const int s = edges[(size_t)e * 2 + 0];
    const int t = edges[(size_t)e * 2 + 1];

    const int ps = atomicAdd(&cursor[s], 1);
    if (ps < CAP) {
        adj[(size_t)s * CAP + ps] = t;
    } else {
        const float* src = vw1 + (size_t)t * D;
        float* dst = out + (size_t)s * D;
        for (int k = 0; k < D; ++k) unsafeAtomicAdd(dst + k, src[k]);
    }

    const int pt = atomicAdd(&cursor[t], 1);
    if (pt < CAP) {
        adj[(size_t)t * CAP + pt] = s;
    } else {
        const float* src = vw1 + (size_t)s * D;
        float* dst = out + (size_t)t * D;
        for (int k = 0; k < D; ++k) unsafeAtomicAdd(dst + k, src[k]);
    }
}

// ---------------------------------------------------------------------------
// Kernel 3: pull-gather. One 16-lane group per vertex; lane owns 4 columns.
// Neighbor IDs read as int4 (4 gathers in flight per group); accumulation and
// the final out += acc are atomic-free (each vertex owned by one group).
// ---------------------------------------------------------------------------
__global__ __launch_bounds__(256) void gather_kernel(
    const int* __restrict__ cursor, const int* __restrict__ adj,
    const float* __restrict__ vw1, float* __restrict__ out, int nverts)
{
    const int gid = blockIdx.x * blockDim.x + threadIdx.x;
    const int v   = gid >> 4;
    if (v >= nverts) return;
    const int sub = (gid & 15) << 2;

    int deg = cursor[v]; if (deg > CAP) deg = CAP;
    const int* nb = adj + (size_t)v * CAP;

    float4 acc = make_float4(0.f, 0.f, 0.f, 0.f);
    int i = 0;
    for (; i + 4 <= deg; i += 4) {
        const int4 u4 = *(const int4*)(nb + i);   // 16B-aligned (CAP%4==0)
        const float4 f0 = *(const float4*)(vw1 + (size_t)u4.x * D + sub);
        const float4 f1 = *(const float4*)(vw1 + (size_t)u4.y * D + sub);
        const float4 f2 = *(const float4*)(vw1 + (size_t)u4.z * D + sub);
        const float4 f3 = *(const float4*)(vw1 + (size_t)u4.w * D + sub);
        acc.x += f0.x + f1.x + f2.x + f3.x;
        acc.y += f0.y + f1.y + f2.y + f3.y;
        acc.z += f0.z + f1.z + f2.z + f3.z;
        acc.w += f0.w + f1.w + f2.w + f3.w;
    }
    for (; i < deg; ++i) {
        const int u = nb[i];
        const float4 f = *(const float4*)(vw1 + (size_t)u * D + sub);
        acc.x += f.x; acc.y += f.y; acc.z += f.z; acc.w += f.w;
    }

    float4* po = (float4*)(out + (size_t)v * D + sub);
    float4 o = *po;
    o.x += acc.x; o.y += acc.y; o.z += acc.z; o.w += acc.w;
    *po = o;
}

// ---------------------------------------------------------------------------
// Fallback (ws too small): round-2's proven atomic scatter.
// ---------------------------------------------------------------------------
__global__ __launch_bounds__(256) void scatter_add_kernel(
    const int* __restrict__ edges, const float* __restrict__ vw1,
    float* __restrict__ out, int nedges)
{
    const int gid = blockIdx.x * blockDim.x + threadIdx.x;
    const int e   = gid >> 4;
    if (e >= nedges) return;
    const int sub = (gid & 15) << 2;
    const int s = edges[(size_t)e * 2 + 0];
    const int t = edges[(size_t)e * 2 + 1];
    const float4 fd = *(const float4*)(vw1 + (size_t)t * D + sub);
    const float4 fs = *(const float4*)(vw1 + (size_t)s * D + sub);
    float* po = out + (size_t)s * D + sub;
    unsafeAtomicAdd(po + 0, fd.x); unsafeAtomicAdd(po + 1, fd.y);
    unsafeAtomicAdd(po + 2, fd.z); unsafeAtomicAdd(po + 3, fd.w);
    float* pt = out + (size_t)t * D + sub;
    unsafeAtomicAdd(pt + 0, fs.x); unsafeAtomicAdd(pt + 1, fs.y);
    unsafeAtomicAdd(pt + 2, fs.z); unsafeAtomicAdd(pt + 3, fs.w);
}

extern "C" void kernel_launch(void* const* d_in, const int* in_sizes, int n_in,
                              void* d_out, int out_size, void* d_ws, size_t ws_size,
                              hipStream_t stream)
{
    const float* verts = (const float*)d_in[0];
    const int*   edges = (const int*)d_in[1];
    const float* w0k   = (const float*)d_in[2];
    const float* w0b   = (const float*)d_in[3];
    const float* w1k   = (const float*)d_in[4];
    const float* w1b   = (const float*)d_in[5];
    float* out = (float*)d_out;

    const int nrows  = in_sizes[0] / D;
    const int nedges = in_sizes[1] / 2;

    // Workspace layout: vw1 | cursor | adj
    const size_t vw1_bytes    = (size_t)nrows * D * sizeof(float);
    const size_t cursor_bytes = (size_t)nrows * sizeof(int);
    const size_t adj_bytes    = (size_t)nrows * CAP * sizeof(int);
    float* vw1  = (float*)d_ws;
    int* cursor = (int*)((char*)d_ws + vw1_bytes);
    int* adj    = (int*)((char*)d_ws + vw1_bytes + cursor_bytes);
    const bool csr_ok = ws_size >= vw1_bytes + cursor_bytes + adj_bytes;

    // GEMM: 64 rows per 256-thread block.
    const int gblocks = (nrows + 63) / 64;
    gemm2_kernel<<<gblocks, 256, 0, stream>>>(verts, w0k, w0b, w1k, w1b,
                                              out, vw1, nrows);

    if (csr_ok) {
        const int zblocks = (nrows + 255) / 256;
        zero_cursor_kernel<<<zblocks, 256, 0, stream>>>(cursor, nrows);
        const int bblocks = (nedges + 255) / 256;
        build_adj_kernel<<<bblocks, 256, 0, stream>>>(edges, cursor, adj,
                                                      vw1, out, nedges);
        const long long ngroups = (long long)nrows * 16;
        const int vblocks = (int)((ngroups + 255) / 256);
        gather_kernel<<<vblocks, 256, 0, stream>>>(cursor, adj, vw1, out, nrows);
    } else {
        const long long ngroups = (long long)nedges * 16;
        const int blocks = (int)((ngroups + 255) / 256);
        scatter_add_kernel<<<blocks, 256, 0, stream>>>(edges, vw1, out, nedges);
    }
}

// Round 9
// 334.276 us; speedup vs baseline: 5.7695x; 5.7695x over previous
//
#include <hip/hip_runtime.h>

#define D 64
#define CAP 64      // adjacency bucket capacity; Poisson(20) => P(deg>64) ~ 1e-17
#define TSTRIDE 68  // tileT row stride (dwords): 16B-aligned b128 rows, 2-way-max banks

// ---------------------------------------------------------------------------
// Kernel 0: zero the cursor array (kernel, not hipMemsetAsync: stay
// unquestionably graph-capture-safe).
// ---------------------------------------------------------------------------
__global__ __launch_bounds__(256) void zero_cursor_kernel(int* __restrict__ cursor,
                                                          int n)
{
    const int i = blockIdx.x * blockDim.x + threadIdx.x;
    if (i < n) cursor[i] = 0;
}

// ---------------------------------------------------------------------------
// Kernel 1: fused dual GEMM — micro-tiled, ALL operands in LDS, only
// accumulators in registers (~56 VGPRs).
// Rounds 5+7 post-mortem: any per-thread float[64] weight array gets spilled
// by the allocator (VGPR pinned at 128, 2.2-4.5 GB scratch traffic, VALUBusy
// <3%). So: weights live in LDS, verts tile lives in LDS transposed, each
// lane computes a 4x4 micro-tile of BOTH products.
//   out  = verts @ w0 + b0   ;   vw1 = verts @ w1 + b1
// Wave w covers cols 16w..16w+15; lane (rg=lane&15, cg=lane>>4) owns rows
// 4rg..4rg+3 x cols 16w+4cg..+3. Per k: a4 = tileT[k][4rg..] (b128, 4-lane
// broadcast), b4 = w{0,1}s[k][c0..] (16-lane broadcast), 32 FMAs.
// ---------------------------------------------------------------------------
__global__ __launch_bounds__(256) void gemm2_kernel(
    const float* __restrict__ verts,
    const float* __restrict__ w0, const float* __restrict__ b0,
    const float* __restrict__ w1, const float* __restrict__ b1,
    float* __restrict__ out, float* __restrict__ vw1, int nrows)
{
    __shared__ float tileT[D][TSTRIDE];   // [k][row], 17.4 KB
    __shared__ float w0s[D][D];           // [k][col], 16 KB
    __shared__ float w1s[D][D];           // [k][col], 16 KB
    __shared__ float b0s[D], b1s[D];

    const int tid  = threadIdx.x;
    const int base = blockIdx.x * 64;
    int rows = nrows - base; if (rows > 64) rows = 64;

    // ---- stage weights + bias (linear float4 copy, coalesced) ----
    {
        const float4* s0 = (const float4*)w0;
        const float4* s1 = (const float4*)w1;
        float4* d0 = (float4*)&w0s[0][0];
        float4* d1 = (float4*)&w1s[0][0];
        for (int j = tid; j < (D * D) / 4; j += 256) { d0[j] = s0[j]; d1[j] = s1[j]; }
        if (tid < D) { b0s[tid] = b0[tid]; b1s[tid] = b1[tid]; }
    }

    // ---- stage verts tile transposed ----
    // thread: row = tid>>2 (64 rows), q = tid&3; reads 4 float4s of its row
    // (fully coalesced per iteration); writes tileT[k][row], k=16q+4it+i.
    // Bank: (4k+row)%32 -> 64 distinct rows per (it,i) => 2-way max (free).
    {
        const int row = tid >> 2;
        const int q   = tid & 3;
        if (row < rows) {
            const float4* src = (const float4*)(verts + (size_t)(base + row) * D);
#pragma unroll
            for (int it = 0; it < 4; ++it) {
                const float4 f = src[q * 4 + it];
                const int k = q * 16 + it * 4;
                tileT[k + 0][row] = f.x;
                tileT[k + 1][row] = f.y;
                tileT[k + 2][row] = f.z;
                tileT[k + 3][row] = f.w;
            }
        }
    }
    __syncthreads();

    // ---- compute: 4x4 micro-tile per lane, both matrices ----
    const int lane = tid & 63;
    const int wid  = tid >> 6;
    const int r0   = (lane & 15) * 4;          // rows 0..60
    const int c0   = wid * 16 + (lane >> 4) * 4; // cols 0..60

    const float4 bias0 = *(const float4*)&b0s[c0];
    const float4 bias1 = *(const float4*)&b1s[c0];
    float4 acc0[4], acc1[4];
#pragma unroll
    for (int i = 0; i < 4; ++i) { acc0[i] = bias0; acc1[i] = bias1; }

#define FMA4(ACC, S, B) \
    ACC.x = fmaf(S, B.x, ACC.x); ACC.y = fmaf(S, B.y, ACC.y); \
    ACC.z = fmaf(S, B.z, ACC.z); ACC.w = fmaf(S, B.w, ACC.w)

#pragma unroll 4
    for (int k = 0; k < D; ++k) {
        const float4 a   = *(const float4*)&tileT[k][r0];
        const float4 bv0 = *(const float4*)&w0s[k][c0];
        const float4 bv1 = *(const float4*)&w1s[k][c0];
        FMA4(acc0[0], a.x, bv0); FMA4(acc0[1], a.y, bv0);
        FMA4(acc0[2], a.z, bv0); FMA4(acc0[3], a.w, bv0);
        FMA4(acc1[0], a.x, bv1); FMA4(acc1[1], a.y, bv1);
        FMA4(acc1[2], a.z, bv1); FMA4(acc1[3], a.w, bv1);
    }
#undef FMA4

    // ---- epilogue: float4 stores, guarded for the tail tile ----
#pragma unroll
    for (int i = 0; i < 4; ++i) {
        const int row = base + r0 + i;
        if (row < nrows) {
            *(float4*)&out[(size_t)row * D + c0] = acc0[i];
            *(float4*)&vw1[(size_t)row * D + c0] = acc1[i];
        }
    }
}

// ---------------------------------------------------------------------------
// Kernel 2: bucket neighbor IDs into fixed-capacity per-vertex lists.
// 2M int atomics on a 400 KB cursor array (vs 128M fp32 atomics in round 2).
// Overflow (statistically impossible here, but correct for any input) falls
// back to direct fp32 atomics into out.
// ---------------------------------------------------------------------------
__global__ __launch_bounds__(256) void build_adj_kernel(
    const int* __restrict__ edges, int* __restrict__ cursor,
    int* __restrict__ adj, const float* __restrict__ vw1,
    float* __restrict__ out, int nedges)
{
    const int e = blockIdx.x * blockDim.x + threadIdx.x;
    if (e >= nedges) return;
    const int s = edges[(size_t)e * 2 + 0];
    const int t = edges[(size_t)e * 2 + 1];

    const int ps = atomicAdd(&cursor[s], 1);
    if (ps < CAP) {
        adj[(size_t)s * CAP + ps] = t;
    } else {
        const float* src = vw1 + (size_t)t * D;
        float* dst = out + (size_t)s * D;
        for (int k = 0; k < D; ++k) unsafeAtomicAdd(dst + k, src[k]);
    }

    const int pt = atomicAdd(&cursor[t], 1);
    if (pt < CAP) {
        adj[(size_t)t * CAP + pt] = s;
    } else {
        const float* src = vw1 + (size_t)s * D;
        float* dst = out + (size_t)t * D;
        for (int k = 0; k < D; ++k) unsafeAtomicAdd(dst + k, src[k]);
    }
}

// ---------------------------------------------------------------------------
// Kernel 3: pull-gather. One 16-lane group per vertex; lane owns 4 columns.
// Neighbor IDs read as int4 (4 gathers in flight per group); accumulation and
// the final out += acc are atomic-free (each vertex owned by one group).
// ---------------------------------------------------------------------------
__global__ __launch_bounds__(256) void gather_kernel(
    const int* __restrict__ cursor, const int* __restrict__ adj,
    const float* __restrict__ vw1, float* __restrict__ out, int nverts)
{
    const int gid = blockIdx.x * blockDim.x + threadIdx.x;
    const int v   = gid >> 4;
    if (v >= nverts) return;
    const int sub = (gid & 15) << 2;

    int deg = cursor[v]; if (deg > CAP) deg = CAP;
    const int* nb = adj + (size_t)v * CAP;

    float4 acc = make_float4(0.f, 0.f, 0.f, 0.f);
    int i = 0;
    for (; i + 4 <= deg; i += 4) {
        const int4 u4 = *(const int4*)(nb + i);   // 16B-aligned (CAP%4==0)
        const float4 f0 = *(const float4*)(vw1 + (size_t)u4.x * D + sub);
        const float4 f1 = *(const float4*)(vw1 + (size_t)u4.y * D + sub);
        const float4 f2 = *(const float4*)(vw1 + (size_t)u4.z * D + sub);
        const float4 f3 = *(const float4*)(vw1 + (size_t)u4.w * D + sub);
        acc.x += f0.x + f1.x + f2.x + f3.x;
        acc.y += f0.y + f1.y + f2.y + f3.y;
        acc.z += f0.z + f1.z + f2.z + f3.z;
        acc.w += f0.w + f1.w + f2.w + f3.w;
    }
    for (; i < deg; ++i) {
        const int u = nb[i];
        const float4 f = *(const float4*)(vw1 + (size_t)u * D + sub);
        acc.x += f.x; acc.y += f.y; acc.z += f.z; acc.w += f.w;
    }

    float4* po = (float4*)(out + (size_t)v * D + sub);
    float4 o = *po;
    o.x += acc.x; o.y += acc.y; o.z += acc.z; o.w += acc.w;
    *po = o;
}

// ---------------------------------------------------------------------------
// Fallback (ws too small): round-2's proven atomic scatter.
// ---------------------------------------------------------------------------
__global__ __launch_bounds__(256) void scatter_add_kernel(
    const int* __restrict__ edges, const float* __restrict__ vw1,
    float* __restrict__ out, int nedges)
{
    const int gid = blockIdx.x * blockDim.x + threadIdx.x;
    const int e   = gid >> 4;
    if (e >= nedges) return;
    const int sub = (gid & 15) << 2;
    const int s = edges[(size_t)e * 2 + 0];
    const int t = edges[(size_t)e * 2 + 1];
    const float4 fd = *(const float4*)(vw1 + (size_t)t * D + sub);
    const float4 fs = *(const float4*)(vw1 + (size_t)s * D + sub);
    float* po = out + (size_t)s * D + sub;
    unsafeAtomicAdd(po + 0, fd.x); unsafeAtomicAdd(po + 1, fd.y);
    unsafeAtomicAdd(po + 2, fd.z); unsafeAtomicAdd(po + 3, fd.w);
    float* pt = out + (size_t)t * D + sub;
    unsafeAtomicAdd(pt + 0, fs.x); unsafeAtomicAdd(pt + 1, fs.y);
    unsafeAtomicAdd(pt + 2, fs.z); unsafeAtomicAdd(pt + 3, fs.w);
}

extern "C" void kernel_launch(void* const* d_in, const int* in_sizes, int n_in,
                              void* d_out, int out_size, void* d_ws, size_t ws_size,
                              hipStream_t stream)
{
    const float* verts = (const float*)d_in[0];
    const int*   edges = (const int*)d_in[1];
    const float* w0k   = (const float*)d_in[2];
    const float* w0b   = (const float*)d_in[3];
    const float* w1k   = (const float*)d_in[4];
    const float* w1b   = (const float*)d_in[5];
    float* out = (float*)d_out;

    const int nrows  = in_sizes[0] / D;
    const int nedges = in_sizes[1] / 2;

    // Workspace layout: vw1 | cursor | adj
    const size_t vw1_bytes    = (size_t)nrows * D * sizeof(float);
    const size_t cursor_bytes = (size_t)nrows * sizeof(int);
    const size_t adj_bytes    = (size_t)nrows * CAP * sizeof(int);
    float* vw1  = (float*)d_ws;
    int* cursor = (int*)((char*)d_ws + vw1_bytes);
    int* adj    = (int*)((char*)d_ws + vw1_bytes + cursor_bytes);
    const bool csr_ok = ws_size >= vw1_bytes + cursor_bytes + adj_bytes;

    // GEMM: 64 rows per 256-thread block.
    const int gblocks = (nrows + 63) / 64;
    gemm2_kernel<<<gblocks, 256, 0, stream>>>(verts, w0k, w0b, w1k, w1b,
                                              out, vw1, nrows);

    if (csr_ok) {
        const int zblocks = (nrows + 255) / 256;
        zero_cursor_kernel<<<zblocks, 256, 0, stream>>>(cursor, nrows);
        const int bblocks = (nedges + 255) / 256;
        build_adj_kernel<<<bblocks, 256, 0, stream>>>(edges, cursor, adj,
                                                      vw1, out, nedges);
        const long long ngroups = (long long)nrows * 16;
        const int vblocks = (int)((ngroups + 255) / 256);
        gather_kernel<<<vblocks, 256, 0, stream>>>(cursor, adj, vw1, out, nrows);
    } else {
        const long long ngroups = (long long)nedges * 16;
        const int blocks = (int)((ngroups + 255) / 256);
        scatter_add_kernel<<<blocks, 256, 0, stream>>>(edges, vw1, out, nedges);
    }
}